// Round 10
// baseline (68.915 us; speedup 1.0000x reference)
//
#include <hip/hip_runtime.h>
#include <math.h>

#define N_CONS  100000
#define N_VARS  200000
#define N_EDGES 8000000
#define N_CAND  20000
#define C_FEAT  5
#define V_FEAT  19
#define BM_WORDS      6250
#define BM_WORDS_PAD  6400            // pad for vector copies
#define ACC_SLOTS     20000           // max distinct candidates
#define CMP_BLOCKS    512             // 2 per CU, 1024 thr -> 32 waves/CU
#define WAVES_TOTAL   (CMP_BLOCKS * 1024 / 64)   // 8192
#define REGION_STRIDE 512             // avg 93 recs/wave, sigma ~9 -> 45 sigma margin
#define ACC_BLOCKS    256             // 1 per CU
#define REGIONS_PER_BLOCK (WAVES_TOTAL / ACC_BLOCKS)  // 32
#define CID_BLOCKS    ((ACC_SLOTS + 255) / 256) // 79

// Pack variable[:,5], constraint[:,2] into dense L2-resident arrays and
// build the candidate bitmap.
__global__ void pack_kernel(const float* __restrict__ variable,
                            const float* __restrict__ constraint,
                            const int* __restrict__ cand,
                            float* __restrict__ var5,
                            float* __restrict__ cons2,
                            unsigned int* __restrict__ bitmap) {
    int i = blockIdx.x * blockDim.x + threadIdx.x;
    if (i < N_VARS) var5[i]  = variable[i * V_FEAT + 5];
    if (i < N_CONS) cons2[i] = constraint[i * C_FEAT + 2];
    if (i < N_CAND) {
        int v = cand[i];
        atomicOr(&bitmap[v >> 5], 1u << (v & 31));
    }
}

// Fused table bp[w] = {bitmap word, exclusive popcount prefix}.
__global__ void __launch_bounds__(1024)
scan_kernel(const unsigned int* __restrict__ bitmap,
            uint2* __restrict__ bp) {
    __shared__ unsigned int wsum[16];
    const int CH = 7;                                   // 7*1024 >= 6400
    int t = threadIdx.x;
    int lane = t & 63, wid = t >> 6;
    int base = t * CH;
    unsigned int w_loc[CH];
    unsigned int pf_loc[CH];
    unsigned int sum = 0;
#pragma unroll
    for (int j = 0; j < CH; ++j) {
        int w = base + j;
        unsigned int word = (w < BM_WORDS_PAD) ? bitmap[w] : 0u;
        w_loc[j]  = word;
        pf_loc[j] = sum;
        sum += __popc(word);
    }
    unsigned int inc = sum;
#pragma unroll
    for (int off = 1; off < 64; off <<= 1) {
        unsigned int n = __shfl_up(inc, off, 64);
        if (lane >= off) inc += n;
    }
    if (lane == 63) wsum[wid] = inc;
    __syncthreads();
    if (wid == 0 && lane < 16) {
        unsigned int v = wsum[lane];
#pragma unroll
        for (int off = 1; off < 16; off <<= 1) {
            unsigned int n = __shfl_up(v, off, 16);
            if (lane >= off) v += n;
        }
        wsum[lane] = v;
    }
    __syncthreads();
    unsigned int ebase = inc - sum + (wid ? wsum[wid - 1] : 0u);
#pragma unroll
    for (int j = 0; j < CH; ++j) {
        int w = base + j;
        if (w < BM_WORDS_PAD) bp[w] = make_uint2(w_loc[j], ebase + pf_loc[j]);
    }
}

// Pass A: stream ONLY v_idx (32 MB, one third of the former 96 MB), test
// against the LDS bp table, ballot-compact {eid, cid} into per-wave private
// regions. Same per-edge filter work as r9; 3x fewer streamed bytes ->
// this dispatch's duration tells us whether the 42us wall is bytes or
// per-edge machinery.
__global__ void __launch_bounds__(1024, 8)
filter_kernel(const int* __restrict__ v_idx,
              const uint2* __restrict__ bp,
              uint2* __restrict__ recs,
              int* __restrict__ wcount) {
    __shared__ uint2 lds_bp[BM_WORDS_PAD];
    {
        const uint4* src = (const uint4*)bp;
        uint4* dst = (uint4*)lds_bp;
        for (int j = threadIdx.x; j < BM_WORDS_PAD / 2; j += blockDim.x)
            dst[j] = src[j];
    }
    __syncthreads();

    const int nch = N_EDGES / 4;
    const int stride = gridDim.x * blockDim.x;
    const int lane = threadIdx.x & 63;
    const unsigned long long lt = (1ull << lane) - 1ull;
    const int wgid = (blockIdx.x * blockDim.x + threadIdx.x) >> 6;
    uint2* region = recs + (size_t)wgid * REGION_STRIDE;
    int woff = 0;   // wave-uniform running record count

    // grid boundary: nch mod (CMP_BLOCKS*1024) = 427136, 64-divisible ->
    // no intra-wave divergence on loop-trip count (ballot-safe).
    for (int g = blockIdx.x * blockDim.x + threadIdx.x; g < nch; g += stride) {
        int4 v = ((const int4*)v_idx)[g];
        int eid0 = 4 * g;

#define SLOT(vv, ee)                                                         \
        {                                                                    \
            uint2 e2 = lds_bp[(vv) >> 5];                                    \
            bool keep = (e2.x >> ((vv) & 31)) & 1u;                          \
            unsigned long long m = __ballot(keep);                           \
            if (keep) {                                                      \
                int cid = (int)e2.y +                                        \
                          __popc(e2.x & ((1u << ((vv) & 31)) - 1u));         \
                int slot = woff + __popcll(m & lt);                          \
                if (slot < REGION_STRIDE)                                    \
                    region[slot] = make_uint2((unsigned)(ee), (unsigned)cid);\
            }                                                                \
            woff += __popcll(m);                                             \
        }
        SLOT(v.x, eid0 + 0)  SLOT(v.y, eid0 + 1)
        SLOT(v.z, eid0 + 2)  SLOT(v.w, eid0 + 3)
#undef SLOT
    }
    if (lane == 0) wcount[wgid] = woff;
}

// Pass B: walk the ~760K dense records; gather the three edge arrays at
// semi-sorted eids (all L3/L2-resident) + var5/cons2 (L2-resident), LDS-
// accumulate by cid, flush coalesced.
__global__ void __launch_bounds__(1024, 4)
accum_kernel(const int* __restrict__ v_idx,
             const int* __restrict__ c_idx,
             const float* __restrict__ edge_attr,
             const float* __restrict__ var5,
             const float* __restrict__ cons2,
             const uint2* __restrict__ recs,
             const int* __restrict__ wcount,
             float* __restrict__ partials) {
    __shared__ float acc[ACC_SLOTS];
    for (int j = threadIdx.x; j < ACC_SLOTS; j += 1024) acc[j] = 0.0f;
    __syncthreads();

    int sub = threadIdx.x >> 7;     // 8 regions processed concurrently
    int idx = threadIdx.x & 127;
    for (int rr = 0; rr < REGIONS_PER_BLOCK; rr += 8) {
        int r = blockIdx.x * REGIONS_PER_BLOCK + rr + sub;
        int cnt = wcount[r];
        if (cnt > REGION_STRIDE) cnt = REGION_STRIDE;
        const uint2* region = recs + (size_t)r * REGION_STRIDE;
        for (int i = idx; i < cnt; i += 128) {
            uint2 rec = region[i];
            int eid = (int)rec.x;
            int v = v_idx[eid];
            float msg = var5[v] * edge_attr[eid] + cons2[c_idx[eid]];
            atomicAdd(&acc[rec.y], msg);
        }
    }
    __syncthreads();

    float4* dst = (float4*)(partials + (size_t)blockIdx.x * ACC_SLOTS);
    const float4* src = (const float4*)acc;
    for (int j = threadIdx.x; j < ACC_SLOTS / 4; j += 1024)
        dst[j] = src[j];
}

// agg2[cid] = sum over the 256 block partials (coalesced columns).
__global__ void reduce_kernel(const float* __restrict__ partials,
                              float* __restrict__ agg2) {
    int cid = blockIdx.x * 256 + threadIdx.x;
    if (cid >= ACC_SLOTS) return;
    float s = 0.0f;
#pragma unroll 8
    for (int k = 0; k < ACC_BLOCKS; ++k)
        s += partials[(size_t)k * ACC_SLOTS + cid];
    agg2[cid] = s;
}

// out[i] = agg * variable[v,0] + sqrt(abs(variable[v,3])), v = cand[i]
__global__ void out_kernel(const int* __restrict__ cand,
                           const float* __restrict__ agg2,
                           const uint2* __restrict__ bp,
                           const float* __restrict__ variable,
                           float* __restrict__ out) {
    int i = blockIdx.x * blockDim.x + threadIdx.x;
    if (i >= N_CAND) return;
    int v = cand[i];
    uint2 e2 = bp[v >> 5];
    int cid = (int)e2.y + __popc(e2.x & ((1u << (v & 31)) - 1u));
    out[i] = agg2[cid] * variable[v * V_FEAT + 0] + sqrtf(fabsf(variable[v * V_FEAT + 3]));
}

extern "C" void kernel_launch(void* const* d_in, const int* in_sizes, int n_in,
                              void* d_out, int out_size, void* d_ws, size_t ws_size,
                              hipStream_t stream) {
    const float* constraint = (const float*)d_in[0];   // [N_CONS, 5]
    const float* variable   = (const float*)d_in[1];   // [N_VARS, 19]
    const int*   cv_edge    = (const int*)d_in[2];     // [2, N_EDGES]
    const float* edge_attr  = (const float*)d_in[3];   // [N_EDGES]
    const int*   cand_mask  = (const int*)d_in[4];     // [N_CAND]
    float* out = (float*)d_out;

    const int* c_idx = cv_edge;            // row 0
    const int* v_idx = cv_edge + N_EDGES;  // row 1

    // ws layout (16B-aligned):
    // var5[200000] f | cons2[100000] f | bitmap[6400] u32 | bp[6400] uint2 |
    // wcount[8192] i | agg2[20000] f | partials[256*20000] f (20.5 MB) |
    // recs[8192*512] uint2 (33.6 MB)      total ~56 MB
    float* var5  = (float*)d_ws;
    float* cons2 = var5 + N_VARS;
    unsigned int* bitmap = (unsigned int*)(cons2 + N_CONS);
    uint2* bp            = (uint2*)(bitmap + BM_WORDS_PAD);
    int*   wcount        = (int*)(bp + BM_WORDS_PAD);
    float* agg2          = (float*)(wcount + WAVES_TOTAL);
    float* partials      = agg2 + ACC_SLOTS;
    uint2* recs          = (uint2*)(partials + (size_t)ACC_BLOCKS * ACC_SLOTS);

    // Only the bitmap needs zeroing (wcount/partials/agg2 fully overwritten;
    // recs only read below wcount).
    hipMemsetAsync(bitmap, 0, BM_WORDS_PAD * sizeof(unsigned int), stream);

    {
        int threads = 256;
        int blocks = (N_VARS + threads - 1) / threads;
        pack_kernel<<<blocks, threads, 0, stream>>>(variable, constraint, cand_mask,
                                                    var5, cons2, bitmap);
    }
    scan_kernel<<<1, 1024, 0, stream>>>(bitmap, bp);
    filter_kernel<<<CMP_BLOCKS, 1024, 0, stream>>>(v_idx, bp, recs, wcount);
    accum_kernel<<<ACC_BLOCKS, 1024, 0, stream>>>(v_idx, c_idx, edge_attr,
                                                  var5, cons2, recs, wcount,
                                                  partials);
    reduce_kernel<<<CID_BLOCKS, 256, 0, stream>>>(partials, agg2);
    {
        int threads = 256;
        int blocks = (N_CAND + threads - 1) / threads;
        out_kernel<<<blocks, threads, 0, stream>>>(cand_mask, agg2, bp, variable, out);
    }
}

// Round 11
// 61.181 us; speedup vs baseline: 1.1264x; 1.1264x over previous
//
#include <hip/hip_runtime.h>
#include <math.h>

#define N_CONS  100000
#define N_VARS  200000
#define N_EDGES 8000000
#define N_CAND  20000
#define C_FEAT  5
#define V_FEAT  19
#define BM_WORDS_PAD  6400            // pad for vector copies
#define ACC_SLOTS     20000           // max distinct candidates
#define EDGE_BLOCKS   256             // 1 per CU
#define CID_BLOCKS    ((ACC_SLOTS + 255) / 256) // 79

// Pack variable[:,5], constraint[:,2] into dense L2-resident arrays and
// build the candidate bitmap.
__global__ void pack_kernel(const float* __restrict__ variable,
                            const float* __restrict__ constraint,
                            const int* __restrict__ cand,
                            float* __restrict__ var5,
                            float* __restrict__ cons2,
                            unsigned int* __restrict__ bitmap) {
    int i = blockIdx.x * blockDim.x + threadIdx.x;
    if (i < N_VARS) var5[i]  = variable[i * V_FEAT + 5];
    if (i < N_CONS) cons2[i] = constraint[i * C_FEAT + 2];
    if (i < N_CAND) {
        int v = cand[i];
        atomicOr(&bitmap[v >> 5], 1u << (v & 31));
    }
}

// Fused table bp[w] = {bitmap word, exclusive popcount prefix}.
__global__ void __launch_bounds__(1024)
scan_kernel(const unsigned int* __restrict__ bitmap,
            uint2* __restrict__ bp) {
    __shared__ unsigned int wsum[16];
    const int CH = 7;                                   // 7*1024 >= 6400
    int t = threadIdx.x;
    int lane = t & 63, wid = t >> 6;
    int base = t * CH;
    unsigned int w_loc[CH];
    unsigned int pf_loc[CH];
    unsigned int sum = 0;
#pragma unroll
    for (int j = 0; j < CH; ++j) {
        int w = base + j;
        unsigned int word = (w < BM_WORDS_PAD) ? bitmap[w] : 0u;
        w_loc[j]  = word;
        pf_loc[j] = sum;
        sum += __popc(word);
    }
    unsigned int inc = sum;
#pragma unroll
    for (int off = 1; off < 64; off <<= 1) {
        unsigned int n = __shfl_up(inc, off, 64);
        if (lane >= off) inc += n;
    }
    if (lane == 63) wsum[wid] = inc;
    __syncthreads();
    if (wid == 0 && lane < 16) {
        unsigned int v = wsum[lane];
#pragma unroll
        for (int off = 1; off < 16; off <<= 1) {
            unsigned int n = __shfl_up(v, off, 16);
            if (lane >= off) v += n;
        }
        wsum[lane] = v;
    }
    __syncthreads();
    unsigned int ebase = inc - sum + (wid ? wsum[wid - 1] : 0u);
#pragma unroll
    for (int j = 0; j < CH; ++j) {
        int w = base + j;
        if (w < BM_WORDS_PAD) bp[w] = make_uint2(w_loc[j], ebase + pf_loc[j]);
    }
}

// Edge phase, r5 monolith with 3-PHASE BATCHED gathers.
// Theory: r5-r8 all ran 43us = ~1640 cyc per 8-edge wave-iter because each
// edge's msg FMA consumed its var5/cons2 gather immediately -> 8 serialized
// L2 round-trips (~200-300cyc each) per iteration. Here: phase1 computes all
// 8 tests/cids (LDS only), phase2 issues all 16 gathers back-to-back
// (branchless, dead lanes pinned to elem 0), sched_barrier, phase3 consumes.
// Latency paid once per 8 edges, overlapped across 16 outstanding loads.
__global__ void __launch_bounds__(1024, 4)
edge_kernel(const int* __restrict__ c_idx,
            const int* __restrict__ v_idx,
            const float* __restrict__ edge_attr,
            const float* __restrict__ var5,
            const float* __restrict__ cons2,
            const uint2* __restrict__ bp,
            float* __restrict__ partials) {
    __shared__ uint2 lds_bp[BM_WORDS_PAD];
    __shared__ float lds_acc[ACC_SLOTS];

    {
        const uint4* src = (const uint4*)bp;
        uint4* dst = (uint4*)lds_bp;
        for (int j = threadIdx.x; j < BM_WORDS_PAD / 2; j += blockDim.x)
            dst[j] = src[j];
        for (int j = threadIdx.x; j < ACC_SLOTS; j += blockDim.x)
            lds_acc[j] = 0.0f;
    }
    __syncthreads();

    const int nch = N_EDGES / 8;            // 8 edges per chunk
    const int stride = gridDim.x * blockDim.x;
    const int4*   v4 = (const int4*)v_idx;
    const int4*   c4 = (const int4*)c_idx;
    const float4* e4 = (const float4*)edge_attr;

    for (int g = blockIdx.x * blockDim.x + threadIdx.x; g < nch; g += stride) {
        int4   va = v4[2 * g],  vb = v4[2 * g + 1];
        int4   ca = c4[2 * g],  cb = c4[2 * g + 1];
        float4 ea = e4[2 * g],  eb = e4[2 * g + 1];

        int   vv[8] = { va.x, va.y, va.z, va.w, vb.x, vb.y, vb.z, vb.w };
        int   cc[8] = { ca.x, ca.y, ca.z, ca.w, cb.x, cb.y, cb.z, cb.w };
        float ee[8] = { ea.x, ea.y, ea.z, ea.w, eb.x, eb.y, eb.z, eb.w };

        // Phase 1: all tests + cids (LDS + VALU only).
        bool keep[8];
        int  cid[8];
#pragma unroll
        for (int k = 0; k < 8; ++k) {
            uint2 e2 = lds_bp[vv[k] >> 5];
            keep[k] = (e2.x >> (vv[k] & 31)) & 1u;
            cid[k]  = (int)e2.y + __popc(e2.x & ((1u << (vv[k] & 31)) - 1u));
        }

        // Phase 2: batch-issue all 16 gathers (unconditional so the
        // compiler cannot sink them under phase-3's branches).
        float v5[8], c2[8];
#pragma unroll
        for (int k = 0; k < 8; ++k) {
            v5[k] = var5[keep[k] ? vv[k] : 0];
            c2[k] = cons2[keep[k] ? cc[k] : 0];
        }
        __builtin_amdgcn_sched_barrier(0);   // pin: all gathers issued here

        // Phase 3: consume (vmcnt counts down as loads retire in order).
#pragma unroll
        for (int k = 0; k < 8; ++k) {
            if (keep[k])
                atomicAdd(&lds_acc[cid[k]], v5[k] * ee[k] + c2[k]);
        }
    }
    __syncthreads();

    // Coalesced flush: partials[block][0..ACC_SLOTS)
    {
        float4* dst = (float4*)(partials + (size_t)blockIdx.x * ACC_SLOTS);
        const float4* src = (const float4*)lds_acc;
        for (int j = threadIdx.x; j < ACC_SLOTS / 4; j += blockDim.x)
            dst[j] = src[j];
    }
}

// agg2[cid] = sum over the 256 block partials (coalesced columns).
__global__ void reduce_kernel(const float* __restrict__ partials,
                              float* __restrict__ agg2) {
    int cid = blockIdx.x * 256 + threadIdx.x;
    if (cid >= ACC_SLOTS) return;
    float s = 0.0f;
#pragma unroll 8
    for (int k = 0; k < EDGE_BLOCKS; ++k)
        s += partials[(size_t)k * ACC_SLOTS + cid];
    agg2[cid] = s;
}

// out[i] = agg * variable[v,0] + sqrt(abs(variable[v,3])), v = cand[i]
__global__ void out_kernel(const int* __restrict__ cand,
                           const float* __restrict__ agg2,
                           const uint2* __restrict__ bp,
                           const float* __restrict__ variable,
                           float* __restrict__ out) {
    int i = blockIdx.x * blockDim.x + threadIdx.x;
    if (i >= N_CAND) return;
    int v = cand[i];
    uint2 e2 = bp[v >> 5];
    int cid = (int)e2.y + __popc(e2.x & ((1u << (v & 31)) - 1u));
    out[i] = agg2[cid] * variable[v * V_FEAT + 0] + sqrtf(fabsf(variable[v * V_FEAT + 3]));
}

extern "C" void kernel_launch(void* const* d_in, const int* in_sizes, int n_in,
                              void* d_out, int out_size, void* d_ws, size_t ws_size,
                              hipStream_t stream) {
    const float* constraint = (const float*)d_in[0];   // [N_CONS, 5]
    const float* variable   = (const float*)d_in[1];   // [N_VARS, 19]
    const int*   cv_edge    = (const int*)d_in[2];     // [2, N_EDGES]
    const float* edge_attr  = (const float*)d_in[3];   // [N_EDGES]
    const int*   cand_mask  = (const int*)d_in[4];     // [N_CAND]
    float* out = (float*)d_out;

    const int* c_idx = cv_edge;            // row 0
    const int* v_idx = cv_edge + N_EDGES;  // row 1

    // ws layout (16B-aligned):
    // var5[200000] f | cons2[100000] f | bitmap[6400] u32 | bp[6400] uint2 |
    // partials[256*20000] f | agg2[20000] f      ~22.3 MB
    float* var5  = (float*)d_ws;
    float* cons2 = var5 + N_VARS;
    unsigned int* bitmap = (unsigned int*)(cons2 + N_CONS);
    uint2* bp            = (uint2*)(bitmap + BM_WORDS_PAD);
    float* partials      = (float*)(bp + BM_WORDS_PAD);
    float* agg2          = partials + (size_t)EDGE_BLOCKS * ACC_SLOTS;

    hipMemsetAsync(bitmap, 0, BM_WORDS_PAD * sizeof(unsigned int), stream);

    {
        int threads = 256;
        int blocks = (N_VARS + threads - 1) / threads;
        pack_kernel<<<blocks, threads, 0, stream>>>(variable, constraint, cand_mask,
                                                    var5, cons2, bitmap);
    }
    scan_kernel<<<1, 1024, 0, stream>>>(bitmap, bp);
    edge_kernel<<<EDGE_BLOCKS, 1024, 0, stream>>>(c_idx, v_idx, edge_attr,
                                                  var5, cons2, bp, partials);
    reduce_kernel<<<CID_BLOCKS, 256, 0, stream>>>(partials, agg2);
    {
        int threads = 256;
        int blocks = (N_CAND + threads - 1) / threads;
        out_kernel<<<blocks, threads, 0, stream>>>(cand_mask, agg2, bp, variable, out);
    }
}